// Round 16
// baseline (125.534 us; speedup 1.0000x reference)
//
#include <hip/hip_runtime.h>
#include <stdint.h>

#define T_LEN 2048

typedef __attribute__((ext_vector_type(8))) short bf16x8;
typedef __attribute__((ext_vector_type(16))) float f32x16;
typedef __attribute__((ext_vector_type(2))) __bf16 bf16x2v;

// RNE fp32 pair -> packed bf16x2 (inputs finite normals)
static __device__ __forceinline__ unsigned pack_bf16(float a, float b) {
    unsigned ua = __float_as_uint(a);
    unsigned ub = __float_as_uint(b);
    ua = (ua + 0x7fffu + ((ua >> 16) & 1u)) >> 16;
    ub = (ub + 0x7fffu + ((ub >> 16) & 1u));
    return (ua & 0xffffu) | (ub & 0xffff0000u);
}

// async global->LDS DMA, 16 B/lane: LDS dest = wave-uniform base + lane*16
static __device__ __forceinline__ void async16(const void* g, void* l) {
    __builtin_amdgcn_global_load_lds(
        (const __attribute__((address_space(1))) unsigned int*)g,
        (__attribute__((address_space(3))) unsigned int*)l, 16, 0, 0);
}

// 2^x on the transcendental pipe (scores carry log2e folded in from prepack)
static __device__ __forceinline__ float fexp2(float x) {
#if __has_builtin(__builtin_amdgcn_exp2f)
    return __builtin_amdgcn_exp2f(x);
#else
    float r; asm("v_exp_f32 %0, %1" : "=v"(r) : "v"(x)); return r;
#endif
}

// v_permlane32_swap_b32 a, b (in-place, inline asm; HW-verified R6):
//   a_new = {a.lo, b.lo}, b_new = {a.hi, b.hi}  (a.hi <-> b.lo)
static __device__ __forceinline__ void swap32(unsigned& a, unsigned& b) {
    asm("v_permlane32_swap_b32 %0, %1" : "+v"(a), "+v"(b));
}

// lp accumulate from a packed bf16x2 word: c + lo + hi (exact; order-insensitive
// since both B elems are 1.0). Verified passing R15.
static __device__ __forceinline__ float lp_acc(unsigned p, float c) {
#if __has_builtin(__builtin_amdgcn_fdot2_f32_bf16)
    bf16x2v a = __builtin_bit_cast(bf16x2v, p);
    bf16x2v one; one[0] = (__bf16)1.0f; one[1] = (__bf16)1.0f;
    return __builtin_amdgcn_fdot2_f32_bf16(a, one, c, false);
#else
    float t0 = __uint_as_float(p << 16);
    float t1 = __uint_as_float(p & 0xffff0000u);
    return c + t0 + t1;
#endif
}

// ---------------------------------------------------------------------------
// Prepack (R15 verbatim):
//   Q: ws+0     bf16 [head][t][swz c]  rows 128B, scaled 0.125*log2(e)
//   K: ws+8MB   bf16 [head][s][swz c]  rows 128B
//   V: ws+16MB  bf16 [head][sTile(64)][c][swz s] rows 128B
// ---------------------------------------------------------------------------
__global__ __launch_bounds__(256)
void prepack(const float* __restrict__ qkv, char* __restrict__ ws)
{
    __shared__ float tile[64 * 130];
    const int tid = threadIdx.x;
    const int b = blockIdx.x;

    if (b < 1024) {                       // ---- Q / K transpose
        const int isK  = b >> 9;
        const int bb   = b & 511;
        const int head = bb >> 4, chunk = bb & 15;
        const float* src = qkv + (size_t)head * 192 * T_LEN
                               + (size_t)(isK ? 64 : 0) * T_LEN;
        const int t0g = chunk * 128;
        const float scale = isK ? 1.0f : 0.18033688f;
#pragma unroll
        for (int i = 0; i < 8; ++i) {
            int p = i * 256 + tid;
            int t4 = p & 31, c = p >> 5;
            float4 v = *(const float4*)(src + (size_t)c * T_LEN + t0g + 4 * t4);
            int a = c * 130 + 4 * t4;
            *(float2*)&tile[a]     = make_float2(v.x, v.y);
            *(float2*)&tile[a + 2] = make_float2(v.z, v.w);
        }
        __syncthreads();
        unsigned* dst = (unsigned*)ws + (size_t)isK * 2097152
                      + (size_t)head * 65536 + (size_t)t0g * 32;
#pragma unroll
        for (int i = 0; i < 16; ++i) {
            int cp = tid & 31, t = i * 8 + (tid >> 5);
            float f0 = tile[(2 * cp) * 130 + t] * scale;
            float f1 = tile[(2 * cp + 1) * 130 + t] * scale;
            dst[t * 32 + (((cp >> 2) ^ (t & 7)) << 2) + (cp & 3)] = pack_bf16(f0, f1);
        }
    } else {                              // ---- V pass-through (swizzle only)
        const int b3 = b - 1024;
        const int head = b3 >> 5, st = b3 & 31;
        const float* src = qkv + (size_t)head * 192 * T_LEN + (size_t)128 * T_LEN;
        const int s0 = st * 64;
        unsigned* dst = (unsigned*)(ws + 16777216) + (size_t)b3 * 2048;
#pragma unroll
        for (int i = 0; i < 4; ++i) {
            int p = i * 256 + tid;
            int s4 = p & 15, c = p >> 4;
            float4 v = *(const float4*)(src + (size_t)c * T_LEN + s0 + 4 * s4);
            int s2a = 2 * s4, s2b = 2 * s4 + 1;
            dst[c * 32 + (((s2a >> 2) ^ (c & 7)) << 2) + (s2a & 3)] = pack_bf16(v.x, v.y);
            dst[c * 32 + (((s2b >> 2) ^ (c & 7)) << 2) + (s2b & 3)] = pack_bf16(v.z, v.w);
        }
    }
}

// ---------------------------------------------------------------------------
// Main: R15 math verbatim; R16 = T15-class software pipeline. Body i:
//   softmax(i) -> barrier -> DMA(i+2) -> QK(i+1) -> PV(i)
// PV(i) and next tile's QK/softmax no longer serialize in the wave's chain.
// Buffers: Ks[2] (tile j -> j&1), Vs[3] (tile j -> j%3). Lifetimes:
//   K slot i&1 rewritten by DMA(i+2) after barrier(i); last read QK(i)
//     pre-barrier(i)  [ok]
//   V slot i%3 rewritten by DMA(i+3) after barrier(i+1); last read PV(i)
//     pre-barrier(i+1)  [ok]
//   DMA(j) drained by the barrier preceding its first read (same per-wave
//     vmcnt-drain-at-barrier semantics as the passing R15 kernel)  [ok]
// LDS: Qs 16K | Ks 16K | Vs 24K | Lb 1K = 58368 B -> still 2 blocks/CU.
// ---------------------------------------------------------------------------
__global__ __launch_bounds__(512, 4)
void attn_fwd(const char* __restrict__ ws, float* __restrict__ out)
{
    __shared__ char smem[58368];
    const int tid  = threadIdx.x;
    const int wave = tid >> 6, lane = tid & 63;
    const int l31  = lane & 31, h = lane >> 5;
    const int wt2  = wave & 3;
    const int wsx  = wave >> 2;
    const int head = blockIdx.x & 31, tb = blockIdx.x >> 5;
    const int swq  = l31 & 7;

    const char* qsrc = ws + (size_t)head * 262144 + (size_t)tb * 16384;
    const char* ksrc = ws + 8388608  + (size_t)head * 262144;
    const char* vsrc = ws + 16777216 + (size_t)head * 262144;

    char*  Qs = smem;                   // [0,16384) — dead after qf; Ob alias
    char*  Ks = smem + 16384;           // 2 x 8KB
    char*  Vs = smem + 32768;           // 3 x 8KB
    float* Lb = (float*)(smem + 57344);
    float* Ob = (float*)smem;           // 64c x 128t fp32, aliases Qs+Ks

    // ---- prologue: Q + tile 0
#pragma unroll
    for (int n = 0; n < 2; ++n) {
        int ch = wave * 2 + n;
        async16(qsrc + ch * 1024 + lane * 16, Qs + ch * 1024);
    }
    async16(ksrc + wave * 1024 + lane * 16, Ks + wave * 1024);
    async16(vsrc + wave * 1024 + lane * 16, Vs + wave * 1024);
    __syncthreads();                    // Q + tile 0 landed

    bf16x8 qf[4];
#pragma unroll
    for (int kb = 0; kb < 4; ++kb)
        qf[kb] = *(const bf16x8*)(Qs + (wt2 * 32 + l31) * 128
                                  + (((kb * 2 + h) ^ swq) << 4));

    f32x16 acc[2];
#pragma unroll
    for (int ct = 0; ct < 2; ++ct)
#pragma unroll
        for (int r = 0; r < 16; ++r) acc[ct][r] = 0.f;

    f32x16 zf;                          // persistent zero C-operand
#pragma unroll
    for (int r = 0; r < 16; ++r) zf[r] = 0.f;

    float lp4[4] = {0.f, 0.f, 0.f, 0.f};
    const int krow = (wsx * 32 + l31) * 128;

    // DMA(1) + QK(0)
    async16(ksrc + 8192 + wave * 1024 + lane * 16, Ks + 8192 + wave * 1024);
    async16(vsrc + 8192 + wave * 1024 + lane * 16, Vs + 8192 + wave * 1024);

    f32x16 sc;
    {
        __builtin_amdgcn_s_setprio(1);
        bf16x8 kf0 = *(const bf16x8*)(Ks + krow + ((h ^ swq) << 4));
        sc = __builtin_amdgcn_mfma_f32_32x32x16_bf16(kf0, qf[0], zf, 0, 0, 0);
#pragma unroll
        for (int kb = 1; kb < 4; ++kb) {
            bf16x8 kf = *(const bf16x8*)(Ks + krow + (((kb * 2 + h) ^ swq) << 4));
            sc = __builtin_amdgcn_mfma_f32_32x32x16_bf16(kf, qf[kb], sc, 0, 0, 0);
        }
        __builtin_amdgcn_s_setprio(0);
    }

    // ---- pipelined main loop
    for (int i = 0; i < 32; ++i) {
        // softmax(i): registers only (sc -> P), no LDS
        union P8 { unsigned u[8]; bf16x8 v[2]; };
        P8 P;
#pragma unroll
        for (int d = 0; d < 8; ++d) {
            unsigned a0 = __float_as_uint(fexp2(sc[2 * d]));
            unsigned a1 = __float_as_uint(fexp2(sc[2 * d + 1]));
            P.u[d] = __builtin_amdgcn_perm(a1, a0, 0x07060302u);
            lp4[d & 3] = lp_acc(P.u[d], lp4[d & 3]);
        }
        swap32(P.u[0], P.u[2]); swap32(P.u[1], P.u[3]);
        swap32(P.u[4], P.u[6]); swap32(P.u[5], P.u[7]);

        if (i < 31) {
            __syncthreads();            // DMA(i+1) landed; all waves past QK(i), PV(i-1)
            if (i <= 29) {              // DMA(i+2)
                async16(ksrc + (size_t)(i + 2) * 8192 + wave * 1024 + lane * 16,
                        Ks + ((i + 2) & 1) * 8192 + wave * 1024);
                async16(vsrc + (size_t)(i + 2) * 8192 + wave * 1024 + lane * 16,
                        Vs + ((i + 2) % 3) * 8192 + wave * 1024);
            }
            // QK(i+1) from Ks[(i+1)&1]
            const char* KsB = Ks + ((i + 1) & 1) * 8192;
            __builtin_amdgcn_s_setprio(1);
            bf16x8 kf0 = *(const bf16x8*)(KsB + krow + ((h ^ swq) << 4));
            f32x16 scn = __builtin_amdgcn_mfma_f32_32x32x16_bf16(kf0, qf[0], zf, 0, 0, 0);
#pragma unroll
            for (int kb = 1; kb < 4; ++kb) {
                bf16x8 kf = *(const bf16x8*)(KsB + krow + (((kb * 2 + h) ^ swq) << 4));
                scn = __builtin_amdgcn_mfma_f32_32x32x16_bf16(kf, qf[kb], scn, 0, 0, 0);
            }
            // PV(i) from Vs[i%3]
            const char* VsB = Vs + (i % 3) * 8192;
#pragma unroll
            for (int kb2 = 0; kb2 < 2; ++kb2) {
                const bf16x8 pfv = kb2 ? P.v[1] : P.v[0];
#pragma unroll
                for (int ct = 0; ct < 2; ++ct) {
                    bf16x8 vf = *(const bf16x8*)(VsB + (ct * 32 + l31) * 128
                                  + (((wsx * 4 + kb2 * 2 + h) ^ swq) << 4));
                    acc[ct] = __builtin_amdgcn_mfma_f32_32x32x16_bf16(vf, pfv, acc[ct], 0, 0, 0);
                }
            }
            __builtin_amdgcn_s_setprio(0);
            sc = scn;
        } else {
            // i == 31: PV only (tile 31 -> slot 1, landed at barrier(30))
            const char* VsB = Vs + ((31 % 3)) * 8192;
            __builtin_amdgcn_s_setprio(1);
#pragma unroll
            for (int kb2 = 0; kb2 < 2; ++kb2) {
                const bf16x8 pfv = kb2 ? P.v[1] : P.v[0];
#pragma unroll
                for (int ct = 0; ct < 2; ++ct) {
                    bf16x8 vf = *(const bf16x8*)(VsB + (ct * 32 + l31) * 128
                                  + (((wsx * 4 + kb2 * 2 + h) ^ swq) << 4));
                    acc[ct] = __builtin_amdgcn_mfma_f32_32x32x16_bf16(vf, pfv, acc[ct], 0, 0, 0);
                }
            }
            __builtin_amdgcn_s_setprio(0);
        }
    }

    __syncthreads();                    // all waves out of the loop (LDS reads done)

    const float lp = (lp4[0] + lp4[1]) + (lp4[2] + lp4[3]);
    float lt = lp + __shfl_xor(lp, 32);
    if (h == 0) Lb[wsx * 128 + wt2 * 32 + l31] = lt;

    if (wsx == 1) {
#pragma unroll
        for (int ct = 0; ct < 2; ++ct)
#pragma unroll
            for (int r = 0; r < 16; ++r) {
                int c = ct * 32 + (r & 3) + 8 * (r >> 2) + 4 * h;
                Ob[c * 128 + wt2 * 32 + l31] = acc[ct][r];
            }
    }
    __syncthreads();

    if (wsx == 0) {
        const float li = 1.0f / (Lb[wt2 * 32 + l31] + Lb[128 + wt2 * 32 + l31]);
#pragma unroll
        for (int ct = 0; ct < 2; ++ct)
#pragma unroll
            for (int r = 0; r < 16; ++r) {
                int c = ct * 32 + (r & 3) + 8 * (r >> 2) + 4 * h;
                float v = acc[ct][r] + Ob[c * 128 + wt2 * 32 + l31];
                out[((size_t)head * 64 + c) * T_LEN + tb * 128 + wt2 * 32 + l31]
                    = v * li;
            }
    }
}

extern "C" void kernel_launch(void* const* d_in, const int* in_sizes, int n_in,
                              void* d_out, int out_size, void* d_ws, size_t ws_size,
                              hipStream_t stream) {
    const float* qkv = (const float*)d_in[0];
    float* out = (float*)d_out;
    char* ws = (char*)d_ws;   // 24 MB
    hipLaunchKernelGGL(prepack, dim3(2048), dim3(256), 0, stream, qkv, ws);
    hipLaunchKernelGGL(attn_fwd, dim3(512), dim3(512), 0, stream, ws, out);
}